// Round 1
// baseline (10957.526 us; speedup 1.0000x reference)
//
#include <hip/hip_runtime.h>
#include <stdint.h>
#include <math.h>

// Problem constants
#define B_DIM 64
#define E_DIM 512
#define H_DIM 1024
#define V_DIM 32000
#define T_STEPS 31
#define GATES 4096          // 4*H
#define OUT_COLS 62         // 2*T

// JAX >= 0.4.36 default: jax_threefry_partitionable = True
#define RNG_PARTITIONABLE 1

// ---------------- threefry2x32 (exact JAX reference) ----------------
__device__ __forceinline__ void tf_round(uint32_t& x0, uint32_t& x1, int r) {
  x0 += x1;
  x1 = (x1 << r) | (x1 >> (32 - r));
  x1 ^= x0;
}

__device__ __forceinline__ void threefry2x32(uint32_t k0, uint32_t k1,
                                             uint32_t& x0, uint32_t& x1) {
  uint32_t k2 = k0 ^ k1 ^ 0x1BD11BDAu;
  x0 += k0; x1 += k1;
  tf_round(x0,x1,13); tf_round(x0,x1,15); tf_round(x0,x1,26); tf_round(x0,x1,6);
  x0 += k1; x1 += k2 + 1u;
  tf_round(x0,x1,17); tf_round(x0,x1,29); tf_round(x0,x1,16); tf_round(x0,x1,24);
  x0 += k2; x1 += k0 + 2u;
  tf_round(x0,x1,13); tf_round(x0,x1,15); tf_round(x0,x1,26); tf_round(x0,x1,6);
  x0 += k0; x1 += k1 + 3u;
  tf_round(x0,x1,17); tf_round(x0,x1,29); tf_round(x0,x1,16); tf_round(x0,x1,24);
  x0 += k1; x1 += k2 + 4u;
  tf_round(x0,x1,13); tf_round(x0,x1,15); tf_round(x0,x1,26); tf_round(x0,x1,6);
  x0 += k2; x1 += k0 + 5u;
}

// ---------------- small utility kernels ----------------
__global__ void add_kernel(const float* __restrict__ a, const float* __restrict__ b,
                           float* __restrict__ o, int n) {
  int i = blockIdx.x * blockDim.x + threadIdx.x;
  if (i < n) o[i] = a[i] + b[i];
}

__global__ void zero_kernel(float* __restrict__ o, int n) {
  int i = blockIdx.x * blockDim.x + threadIdx.x;
  if (i < n) o[i] = 0.0f;
}

__global__ void copy_kernel(const float* __restrict__ a, float* __restrict__ o, int n) {
  int i = blockIdx.x * blockDim.x + threadIdx.x;
  if (i < n) o[i] = a[i];
}

// ---------------- fp32 GEMM: C(64 x N) = A(64 x K) @ W(K x N), split-K ----------------
// Block: 256 threads, tile 64 rows x 256 cols, k-chunk = K/gridDim.y.
// Writes partial sums P[ks][64][N] (deterministic reduction later).
__global__ __launch_bounds__(256, 2)
void gemm64_kernel(const float* __restrict__ A, const float* __restrict__ W,
                   float* __restrict__ P, int K, int N) {
  const int vt = blockIdx.x;
  const int ks = blockIdx.y;
  const int kchunk = K / gridDim.y;
  const int kbase = ks * kchunk;
  const int v0 = vt * 256;

  __shared__ float As[32][68];   // +4 pad: keeps 16B alignment, spreads banks
  __shared__ float Ws[32][256];

  float acc[8][8];
#pragma unroll
  for (int i = 0; i < 8; i++)
#pragma unroll
    for (int j = 0; j < 8; j++) acc[i][j] = 0.0f;

  const int tid = threadIdx.x;
  const int cg4 = (tid & 31) * 4;   // col group base (and +128)
  const int rg4 = (tid >> 5) * 4;   // row group base (and +32)

  for (int k0 = kbase; k0 < kbase + kchunk; k0 += 32) {
    __syncthreads();
    // stage A (64 x 32), transposed into As[k][b]
    {
      int b  = tid >> 3;       // 0..31
      int f4 = tid & 7;        // k sub-offset
      const float* Ab = A + (size_t)b * K + k0 + f4 * 4;
      float4 a0 = *(const float4*)Ab;
      float4 a1 = *(const float4*)(Ab + (size_t)32 * K);
      int kk0 = f4 * 4;
      As[kk0+0][b] = a0.x; As[kk0+1][b] = a0.y; As[kk0+2][b] = a0.z; As[kk0+3][b] = a0.w;
      As[kk0+0][b+32] = a1.x; As[kk0+1][b+32] = a1.y; As[kk0+2][b+32] = a1.z; As[kk0+3][b+32] = a1.w;
    }
    // stage W (32 x 256)
#pragma unroll
    for (int p = 0; p < 8; p++) {
      int idx = tid + p * 256;
      int row = idx >> 6, c4 = idx & 63;
      *(float4*)&Ws[row][c4 * 4] =
          *(const float4*)(W + (size_t)(k0 + row) * N + v0 + c4 * 4);
    }
    __syncthreads();

#pragma unroll 8
    for (int kk = 0; kk < 32; kk++) {
      float4 a0 = *(const float4*)&As[kk][rg4];
      float4 a1 = *(const float4*)&As[kk][32 + rg4];
      float4 w0 = *(const float4*)&Ws[kk][cg4];
      float4 w1 = *(const float4*)&Ws[kk][128 + cg4];
      float av[8] = {a0.x, a0.y, a0.z, a0.w, a1.x, a1.y, a1.z, a1.w};
      float wv[8] = {w0.x, w0.y, w0.z, w0.w, w1.x, w1.y, w1.z, w1.w};
#pragma unroll
      for (int i = 0; i < 8; i++)
#pragma unroll
        for (int j = 0; j < 8; j++)
          acc[i][j] = fmaf(av[i], wv[j], acc[i][j]);
    }
  }

  const size_t base = (size_t)ks * 64 * N;
#pragma unroll
  for (int i = 0; i < 8; i++) {
    int row = (i < 4) ? (rg4 + i) : (32 + rg4 + i - 4);
    float4 s0 = make_float4(acc[i][0], acc[i][1], acc[i][2], acc[i][3]);
    float4 s1 = make_float4(acc[i][4], acc[i][5], acc[i][6], acc[i][7]);
    *(float4*)(P + base + (size_t)row * N + v0 + cg4) = s0;
    *(float4*)(P + base + (size_t)row * N + v0 + 128 + cg4) = s1;
  }
}

// ---------------- LSTM gate fusion ----------------
// z = sum_p zparts[p] + bias ; i,f,g,o = split(z) ; c' = sig(f)*c + sig(i)*g ; h' = sig(o)*c'
__global__ void gates_kernel(const float* __restrict__ zp, int ksplit,
                             const float* __restrict__ bias,
                             const float* __restrict__ c_in,
                             float* __restrict__ h_out, float* __restrict__ c_out) {
  int tid = blockIdx.x * blockDim.x + threadIdx.x;
  if (tid >= B_DIM * H_DIM) return;
  int b = tid >> 10, j = tid & 1023;
  float zi = bias[j], zf = bias[j + 1024], zg = bias[j + 2048], zo = bias[j + 3072];
  const float* Pb = zp + (size_t)b * GATES;
  for (int p = 0; p < ksplit; p++) {
    const float* P = Pb + (size_t)p * B_DIM * GATES;
    zi += P[j]; zf += P[j + 1024]; zg += P[j + 2048]; zo += P[j + 3072];
  }
  float cp = c_in ? c_in[tid] : 0.0f;
  float si = 1.0f / (1.0f + expf(-zi));
  float sf = 1.0f / (1.0f + expf(-zf));
  float so = 1.0f / (1.0f + expf(-zo));
  float c = sf * cp + si * zg;     // g is linear (activation=None)
  c_out[tid] = c;
  h_out[tid] = so * c;             // linear activation on cell output
}

// ---------------- softmax stats + exact JAX categorical sampling ----------------
// one block per batch row; logits = sum_p lparts[p] + bd
__global__ __launch_bounds__(256)
void sample_kernel(const float* __restrict__ lp4, int ksplit,
                   const float* __restrict__ bd, int t,
                   float* __restrict__ out) {
  const int b = blockIdx.x;
  const int tid = threadIdx.x;

  // key_t = fold_in(key(1234), t) = threefry((0,1234),(0,t))
  uint32_t tk0 = 0u, tk1 = (uint32_t)t;
  threefry2x32(0u, 1234u, tk0, tk1);

  const size_t rowoff = (size_t)b * V_DIM;
  float m = -INFINITY, best = -INFINITY;
  int bi = 0;

  for (int v = tid; v < V_DIM; v += 256) {
    float l = bd[v];
    for (int p = 0; p < ksplit; p++) l += lp4[(size_t)p * B_DIM * V_DIM + rowoff + v];
    m = fmaxf(m, l);

    uint32_t j = (uint32_t)(b * V_DIM + v);
    uint32_t bits;
#if RNG_PARTITIONABLE
    uint32_t y0 = 0u, y1 = j;
    threefry2x32(tk0, tk1, y0, y1);
    bits = y0 ^ y1;
#else
    const uint32_t half = (uint32_t)(B_DIM * V_DIM / 2);
    uint32_t y0, y1;
    if (j < half) { y0 = j; y1 = j + half; } else { y0 = j - half; y1 = j; }
    threefry2x32(tk0, tk1, y0, y1);
    bits = (j < half) ? y0 : y1;
#endif
    // JAX uniform: ((bits>>9)|0x3f800000) - 1, then clamp to tiny
    uint32_t fb = (bits >> 9) | 0x3f800000u;
    float u = __uint_as_float(fb) - 1.0f;
    u = fmaxf(u, 1.17549435e-38f);
    float g = -logf(-logf(u));
    float val = l + g;
    if (val > best) { best = val; bi = v; }   // strict > keeps lowest index on tie
  }

  __shared__ float sm[4], sb[4], sS[4], sT[4];
  __shared__ int sbi[4];
  __shared__ float bm_s;
  __shared__ int bi_s;

  // wave reduce (64-wide)
  for (int off = 32; off > 0; off >>= 1) {
    float om = __shfl_down(m, off);
    float ob = __shfl_down(best, off);
    int   oi = __shfl_down(bi, off);
    m = fmaxf(m, om);
    if (ob > best || (ob == best && oi < bi)) { best = ob; bi = oi; }
  }
  int wave = tid >> 6, lane = tid & 63;
  if (lane == 0) { sm[wave] = m; sb[wave] = best; sbi[wave] = bi; }
  __syncthreads();
  if (tid == 0) {
    float M = sm[0], Bv = sb[0]; int BI = sbi[0];
    for (int w = 1; w < 4; w++) {
      M = fmaxf(M, sm[w]);
      if (sb[w] > Bv || (sb[w] == Bv && sbi[w] < BI)) { Bv = sb[w]; BI = sbi[w]; }
    }
    bm_s = M; bi_s = BI;
  }
  __syncthreads();
  const float bm = bm_s;

  // phase B: s = sum exp(l-m), t2 = sum exp(l-m)*l   (re-read, deterministic)
  float s = 0.0f, t2 = 0.0f;
  for (int v = tid; v < V_DIM; v += 256) {
    float l = bd[v];
    for (int p = 0; p < ksplit; p++) l += lp4[(size_t)p * B_DIM * V_DIM + rowoff + v];
    float e = expf(l - bm);
    s += e;
    t2 += e * l;
  }
  for (int off = 32; off > 0; off >>= 1) {
    s  += __shfl_down(s, off);
    t2 += __shfl_down(t2, off);
  }
  if (lane == 0) { sS[wave] = s; sT[wave] = t2; }
  __syncthreads();
  if (tid == 0) {
    float S  = sS[0] + sS[1] + sS[2] + sS[3];
    float T2 = sT[0] + sT[1] + sT[2] + sT[3];
    int BI = bi_s;
    float lbest = bd[BI];
    for (int p = 0; p < ksplit; p++) lbest += lp4[(size_t)p * B_DIM * V_DIM + rowoff + BI];
    float lse = bm + logf(S);
    out[(size_t)b * OUT_COLS + t]          = (float)BI;        // msg
    out[3968 + (size_t)b * OUT_COLS + t]   = lbest - lse;      // log_prob
    out[7936 + (size_t)b * OUT_COLS + t]   = lse - T2 / S;     // entropy
  }
}

// ---------------- launcher ----------------
extern "C" void kernel_launch(void* const* d_in, const int* in_sizes, int n_in,
                              void* d_out, int out_size, void* d_ws, size_t ws_size,
                              hipStream_t stream) {
  const float* inp = (const float*)d_in[0];
  const float* Wx1 = (const float*)d_in[1];
  // d_in[2] = Wh1: unused (encoder initial h == 0)
  const float* b1  = (const float*)d_in[3];
  const float* Wx2 = (const float*)d_in[4];
  const float* Wh2 = (const float*)d_in[5];
  const float* b2  = (const float*)d_in[6];
  const float* Wd  = (const float*)d_in[7];
  const float* bd  = (const float*)d_in[8];
  float* out = (float*)d_out;

  float* ws = (float*)d_ws;
  float* W2c    = ws;                    // 1024*4096           = 4,194,304
  float* zparts = W2c + 4194304;         // 16 * 64*4096        = 4,194,304
  float* lparts = zparts + 4194304;      // 4  * 64*32000       = 8,192,000
  float* h      = lparts + 8192000;      // 65,536
  float* c      = h + 65536;             // 65,536

  // precompute W2c = Wx2 + Wh2 (decoder feeds x == h)
  add_kernel<<<16384, 256, 0, stream>>>(Wx2, Wh2, W2c, 4194304);
  // zero the msg/lp/ent pad region (cols 31..61) + everything we then overwrite
  zero_kernel<<<47, 256, 0, stream>>>(out, 11904);

  // encoder: single step, zero initial state -> z = x@Wx1 + b1
  gemm64_kernel<<<dim3(16, 4), 256, 0, stream>>>(inp, Wx1, zparts, E_DIM, GATES);
  gates_kernel<<<256, 256, 0, stream>>>(zparts, 4, b1, nullptr, h, c);

  for (int t = 0; t < T_STEPS; t++) {
    gemm64_kernel<<<dim3(16, 16), 256, 0, stream>>>(h, W2c, zparts, H_DIM, GATES);
    gates_kernel<<<256, 256, 0, stream>>>(zparts, 16, b2, c, h, c);
    gemm64_kernel<<<dim3(125, 4), 256, 0, stream>>>(h, Wd, lparts, H_DIM, V_DIM);
    sample_kernel<<<64, 256, 0, stream>>>(lparts, 4, bd, t, out);
  }

  copy_kernel<<<256, 256, 0, stream>>>(h, out + 11904, B_DIM * H_DIM);
}

// Round 2
// 3588.393 us; speedup vs baseline: 3.0536x; 3.0536x over previous
//
#include <hip/hip_runtime.h>
#include <stdint.h>
#include <math.h>

// Problem constants
#define B_DIM 64
#define E_DIM 512
#define H_DIM 1024
#define V_DIM 32000
#define T_STEPS 31
#define GATES 4096          // 4*H
#define OUT_COLS 62         // 2*T
#define NCHUNK 125          // 32000 / 256

// JAX >= 0.4.36 default: jax_threefry_partitionable = True
#define RNG_PARTITIONABLE 1

// ---------------- threefry2x32 (exact JAX reference) ----------------
__device__ __forceinline__ void tf_round(uint32_t& x0, uint32_t& x1, int r) {
  x0 += x1;
  x1 = (x1 << r) | (x1 >> (32 - r));
  x1 ^= x0;
}

__device__ __forceinline__ void threefry2x32(uint32_t k0, uint32_t k1,
                                             uint32_t& x0, uint32_t& x1) {
  uint32_t k2 = k0 ^ k1 ^ 0x1BD11BDAu;
  x0 += k0; x1 += k1;
  tf_round(x0,x1,13); tf_round(x0,x1,15); tf_round(x0,x1,26); tf_round(x0,x1,6);
  x0 += k1; x1 += k2 + 1u;
  tf_round(x0,x1,17); tf_round(x0,x1,29); tf_round(x0,x1,16); tf_round(x0,x1,24);
  x0 += k2; x1 += k0 + 2u;
  tf_round(x0,x1,13); tf_round(x0,x1,15); tf_round(x0,x1,26); tf_round(x0,x1,6);
  x0 += k0; x1 += k1 + 3u;
  tf_round(x0,x1,17); tf_round(x0,x1,29); tf_round(x0,x1,16); tf_round(x0,x1,24);
  x0 += k1; x1 += k2 + 4u;
  tf_round(x0,x1,13); tf_round(x0,x1,15); tf_round(x0,x1,26); tf_round(x0,x1,6);
  x0 += k2; x1 += k0 + 5u;
}

// ---------------- small utility kernels ----------------
__global__ void add_kernel(const float* __restrict__ a, const float* __restrict__ b,
                           float* __restrict__ o, int n) {
  int i = blockIdx.x * blockDim.x + threadIdx.x;
  if (i < n) o[i] = a[i] + b[i];
}

__global__ void zero_kernel(float* __restrict__ o, int n) {
  int i = blockIdx.x * blockDim.x + threadIdx.x;
  if (i < n) o[i] = 0.0f;
}

__global__ void copy_kernel(const float* __restrict__ a, float* __restrict__ o, int n) {
  int i = blockIdx.x * blockDim.x + threadIdx.x;
  if (i < n) o[i] = a[i];
}

// ---------------- fp32 GEMM: C(64 x N) = A(64 x K) @ W(K x N), split-K ----------------
__global__ __launch_bounds__(256, 2)
void gemm64_kernel(const float* __restrict__ A, const float* __restrict__ W,
                   float* __restrict__ P, int K, int N) {
  const int vt = blockIdx.x;
  const int ks = blockIdx.y;
  const int kchunk = K / gridDim.y;
  const int kbase = ks * kchunk;
  const int v0 = vt * 256;

  __shared__ float As[32][68];
  __shared__ float Ws[32][256];

  float acc[8][8];
#pragma unroll
  for (int i = 0; i < 8; i++)
#pragma unroll
    for (int j = 0; j < 8; j++) acc[i][j] = 0.0f;

  const int tid = threadIdx.x;
  const int cg4 = (tid & 31) * 4;
  const int rg4 = (tid >> 5) * 4;

  for (int k0 = kbase; k0 < kbase + kchunk; k0 += 32) {
    __syncthreads();
    {
      int b  = tid >> 3;
      int f4 = tid & 7;
      const float* Ab = A + (size_t)b * K + k0 + f4 * 4;
      float4 a0 = *(const float4*)Ab;
      float4 a1 = *(const float4*)(Ab + (size_t)32 * K);
      int kk0 = f4 * 4;
      As[kk0+0][b] = a0.x; As[kk0+1][b] = a0.y; As[kk0+2][b] = a0.z; As[kk0+3][b] = a0.w;
      As[kk0+0][b+32] = a1.x; As[kk0+1][b+32] = a1.y; As[kk0+2][b+32] = a1.z; As[kk0+3][b+32] = a1.w;
    }
#pragma unroll
    for (int p = 0; p < 8; p++) {
      int idx = tid + p * 256;
      int row = idx >> 6, c4 = idx & 63;
      *(float4*)&Ws[row][c4 * 4] =
          *(const float4*)(W + (size_t)(k0 + row) * N + v0 + c4 * 4);
    }
    __syncthreads();

#pragma unroll 8
    for (int kk = 0; kk < 32; kk++) {
      float4 a0 = *(const float4*)&As[kk][rg4];
      float4 a1 = *(const float4*)&As[kk][32 + rg4];
      float4 w0 = *(const float4*)&Ws[kk][cg4];
      float4 w1 = *(const float4*)&Ws[kk][128 + cg4];
      float av[8] = {a0.x, a0.y, a0.z, a0.w, a1.x, a1.y, a1.z, a1.w};
      float wv[8] = {w0.x, w0.y, w0.z, w0.w, w1.x, w1.y, w1.z, w1.w};
#pragma unroll
      for (int i = 0; i < 8; i++)
#pragma unroll
        for (int j = 0; j < 8; j++)
          acc[i][j] = fmaf(av[i], wv[j], acc[i][j]);
    }
  }

  const size_t base = (size_t)ks * 64 * N;
#pragma unroll
  for (int i = 0; i < 8; i++) {
    int row = (i < 4) ? (rg4 + i) : (32 + rg4 + i - 4);
    float4 s0 = make_float4(acc[i][0], acc[i][1], acc[i][2], acc[i][3]);
    float4 s1 = make_float4(acc[i][4], acc[i][5], acc[i][6], acc[i][7]);
    *(float4*)(P + base + (size_t)row * N + v0 + cg4) = s0;
    *(float4*)(P + base + (size_t)row * N + v0 + 128 + cg4) = s1;
  }
}

// ---------------- LSTM gate fusion ----------------
__global__ void gates_kernel(const float* __restrict__ zp, int ksplit,
                             const float* __restrict__ bias,
                             const float* __restrict__ c_in,
                             float* __restrict__ h_out, float* __restrict__ c_out) {
  int tid = blockIdx.x * blockDim.x + threadIdx.x;
  if (tid >= B_DIM * H_DIM) return;
  int b = tid >> 10, j = tid & 1023;
  float zi = bias[j], zf = bias[j + 1024], zg = bias[j + 2048], zo = bias[j + 3072];
  const float* Pb = zp + (size_t)b * GATES;
  for (int p = 0; p < ksplit; p++) {
    const float* P = Pb + (size_t)p * B_DIM * GATES;
    zi += P[j]; zf += P[j + 1024]; zg += P[j + 2048]; zo += P[j + 3072];
  }
  float cp = c_in ? c_in[tid] : 0.0f;
  float si = 1.0f / (1.0f + expf(-zi));
  float sf = 1.0f / (1.0f + expf(-zf));
  float so = 1.0f / (1.0f + expf(-zo));
  float c = sf * cp + si * zg;
  c_out[tid] = c;
  h_out[tid] = so * c;
}

// ---------------- sampling stage 1: per-chunk partials ----------------
// grid (NCHUNK, B): each block handles 256 vocab entries of one row.
// Emits: chunk max m, chunk best (gumbel val, idx), locally-scaled
// s = sum exp(l-m), t2 = sum exp(l-m)*l.
__global__ __launch_bounds__(256)
void sample_stage1(const float* __restrict__ lp4, int ksplit,
                   const float* __restrict__ bd, int t,
                   float* __restrict__ pm, float* __restrict__ ps,
                   float* __restrict__ pt2, float* __restrict__ pbest,
                   int* __restrict__ pbi) {
  const int chunk = blockIdx.x;
  const int b = blockIdx.y;
  const int v = chunk * 256 + threadIdx.x;
  const size_t rowoff = (size_t)b * V_DIM;

  float l = bd[v];
  for (int p = 0; p < ksplit; p++)
    l += lp4[(size_t)p * B_DIM * V_DIM + rowoff + v];

  // key_t = fold_in(key(1234), t); per-element counter (partitionable mode)
  uint32_t tk0 = 0u, tk1 = (uint32_t)t;
  threefry2x32(0u, 1234u, tk0, tk1);
  uint32_t j = (uint32_t)(b * V_DIM + v);
#if RNG_PARTITIONABLE
  uint32_t y0 = 0u, y1 = j;
  threefry2x32(tk0, tk1, y0, y1);
  uint32_t bits = y0 ^ y1;
#else
  const uint32_t half = (uint32_t)(B_DIM * V_DIM / 2);
  uint32_t y0, y1;
  if (j < half) { y0 = j; y1 = j + half; } else { y0 = j - half; y1 = j; }
  threefry2x32(tk0, tk1, y0, y1);
  uint32_t bits = (j < half) ? y0 : y1;
#endif
  float u = __uint_as_float((bits >> 9) | 0x3f800000u) - 1.0f;
  u = fmaxf(u, 1.17549435e-38f);
  float g = -logf(-logf(u));
  float val = l + g;
  int bi = v;

  // block reduce: max(l), argmax(val) with lowest-index tie-break
  float m = l, bv = val;
  for (int off = 32; off > 0; off >>= 1) {
    m = fmaxf(m, __shfl_down(m, off));
    float ob = __shfl_down(bv, off);
    int   oi = __shfl_down(bi, off);
    if (ob > bv || (ob == bv && oi < bi)) { bv = ob; bi = oi; }
  }
  __shared__ float sm[4], sb2[4], ss[4], st[4];
  __shared__ int sbi[4];
  __shared__ float Msh;
  int wave = threadIdx.x >> 6, lane = threadIdx.x & 63;
  if (lane == 0) { sm[wave] = m; sb2[wave] = bv; sbi[wave] = bi; }
  __syncthreads();
  if (threadIdx.x == 0) {
    float M = sm[0], Bv = sb2[0]; int BI = sbi[0];
    for (int w = 1; w < 4; w++) {
      M = fmaxf(M, sm[w]);
      if (sb2[w] > Bv || (sb2[w] == Bv && sbi[w] < BI)) { Bv = sb2[w]; BI = sbi[w]; }
    }
    Msh = M;
    int o = b * NCHUNK + chunk;
    pm[o] = M; pbest[o] = Bv; pbi[o] = BI;
  }
  __syncthreads();
  float e = expf(l - Msh);
  float t2 = e * l;
  for (int off = 32; off > 0; off >>= 1) {
    e  += __shfl_down(e, off);
    t2 += __shfl_down(t2, off);
  }
  if (lane == 0) { ss[wave] = e; st[wave] = t2; }
  __syncthreads();
  if (threadIdx.x == 0) {
    int o = b * NCHUNK + chunk;
    ps[o]  = ss[0] + ss[1] + ss[2] + ss[3];
    pt2[o] = st[0] + st[1] + st[2] + st[3];
  }
}

// ---------------- sampling stage 2: reduce 125 chunks per row ----------------
__global__ __launch_bounds__(128)
void sample_stage2(const float* __restrict__ pm, const float* __restrict__ ps,
                   const float* __restrict__ pt2, const float* __restrict__ pbest,
                   const int* __restrict__ pbi,
                   const float* __restrict__ lp4, int ksplit,
                   const float* __restrict__ bd, int t, float* __restrict__ out) {
  const int b = blockIdx.x;
  const int tid = threadIdx.x;
  const int o = b * NCHUNK + tid;
  const bool valid = tid < NCHUNK;

  float m  = valid ? pm[o]    : -INFINITY;
  float bv = valid ? pbest[o] : -INFINITY;
  int   bi = valid ? pbi[o]   : 0x7fffffff;

  // global max over chunks
  float M = m;
  for (int off = 32; off > 0; off >>= 1) M = fmaxf(M, __shfl_down(M, off));
  __shared__ float sM[2];
  int wave = tid >> 6, lane = tid & 63;
  if (lane == 0) sM[wave] = M;
  __syncthreads();
  const float Mg = fmaxf(sM[0], sM[1]);

  float sc = valid ? expf(m - Mg) : 0.0f;
  float s  = valid ? ps[o]  * sc : 0.0f;
  float t2 = valid ? pt2[o] * sc : 0.0f;
  for (int off = 32; off > 0; off >>= 1) {
    s  += __shfl_down(s, off);
    t2 += __shfl_down(t2, off);
    float ob = __shfl_down(bv, off);
    int   oi = __shfl_down(bi, off);
    if (ob > bv || (ob == bv && oi < bi)) { bv = ob; bi = oi; }
  }
  __shared__ float sS[2], sT[2], sB[2];
  __shared__ int sI[2];
  if (lane == 0) { sS[wave] = s; sT[wave] = t2; sB[wave] = bv; sI[wave] = bi; }
  __syncthreads();
  if (tid == 0) {
    float S = sS[0] + sS[1], T2 = sT[0] + sT[1];
    float Bv = sB[0]; int BI = sI[0];
    if (sB[1] > Bv || (sB[1] == Bv && sI[1] < BI)) { Bv = sB[1]; BI = sI[1]; }
    float lbest = bd[BI];
    for (int p = 0; p < ksplit; p++)
      lbest += lp4[(size_t)p * B_DIM * V_DIM + (size_t)b * V_DIM + BI];
    float lse = Mg + logf(S);
    out[(size_t)b * OUT_COLS + t]        = (float)BI;     // msg
    out[3968 + (size_t)b * OUT_COLS + t] = lbest - lse;   // log_prob
    out[7936 + (size_t)b * OUT_COLS + t] = lse - T2 / S;  // entropy
  }
}

// ---------------- launcher ----------------
extern "C" void kernel_launch(void* const* d_in, const int* in_sizes, int n_in,
                              void* d_out, int out_size, void* d_ws, size_t ws_size,
                              hipStream_t stream) {
  const float* inp = (const float*)d_in[0];
  const float* Wx1 = (const float*)d_in[1];
  // d_in[2] = Wh1: unused (encoder initial h == 0)
  const float* b1  = (const float*)d_in[3];
  const float* Wx2 = (const float*)d_in[4];
  const float* Wh2 = (const float*)d_in[5];
  const float* b2  = (const float*)d_in[6];
  const float* Wd  = (const float*)d_in[7];
  const float* bd  = (const float*)d_in[8];
  float* out = (float*)d_out;

  float* ws = (float*)d_ws;
  float* W2c    = ws;                    // 1024*4096           = 4,194,304
  float* zparts = W2c + 4194304;         // 16 * 64*4096        = 4,194,304
  float* lparts = zparts + 4194304;      // 4  * 64*32000       = 8,192,000
  float* h      = lparts + 8192000;      // 65,536
  float* c      = h + 65536;             // 65,536

  // sampling partials alias zparts (dead during sampling phase of each step)
  float* pm    = zparts;                 // 8000
  float* ps    = zparts + 8000;          // 8000
  float* pt2   = zparts + 16000;         // 8000
  float* pbest = zparts + 24000;         // 8000
  int*   pbi   = (int*)(zparts + 32000); // 8000

  add_kernel<<<16384, 256, 0, stream>>>(Wx2, Wh2, W2c, 4194304);
  zero_kernel<<<47, 256, 0, stream>>>(out, 11904);

  // encoder: single step, zero initial state -> z = x@Wx1 + b1
  gemm64_kernel<<<dim3(16, 4), 256, 0, stream>>>(inp, Wx1, zparts, E_DIM, GATES);
  gates_kernel<<<256, 256, 0, stream>>>(zparts, 4, b1, nullptr, h, c);

  for (int t = 0; t < T_STEPS; t++) {
    gemm64_kernel<<<dim3(16, 16), 256, 0, stream>>>(h, W2c, zparts, H_DIM, GATES);
    gates_kernel<<<256, 256, 0, stream>>>(zparts, 16, b2, c, h, c);
    gemm64_kernel<<<dim3(125, 4), 256, 0, stream>>>(h, Wd, lparts, H_DIM, V_DIM);
    sample_stage1<<<dim3(NCHUNK, B_DIM), 256, 0, stream>>>(lparts, 4, bd, t,
                                                           pm, ps, pt2, pbest, pbi);
    sample_stage2<<<B_DIM, 128, 0, stream>>>(pm, ps, pt2, pbest, pbi,
                                             lparts, 4, bd, t, out);
  }

  copy_kernel<<<256, 256, 0, stream>>>(h, out + 11904, B_DIM * H_DIM);
}

// Round 3
// 2370.462 us; speedup vs baseline: 4.6225x; 1.5138x over previous
//
#include <hip/hip_runtime.h>
#include <stdint.h>
#include <math.h>

// Problem constants
#define B_DIM 64
#define E_DIM 512
#define H_DIM 1024
#define V_DIM 32000
#define T_STEPS 31
#define GATES 4096          // 4*H
#define OUT_COLS 62         // 2*T
#define NCHUNK 125          // 32000 / 256
#define STOT 32             // K=1024 -> 32 k-steps of 32

// JAX >= 0.4.36 default: jax_threefry_partitionable = True
#define RNG_PARTITIONABLE 1

typedef _Float16 half8 __attribute__((ext_vector_type(8)));
typedef float floatx4 __attribute__((ext_vector_type(4)));

// ---------------- threefry2x32 (exact JAX reference) ----------------
__device__ __forceinline__ void tf_round(uint32_t& x0, uint32_t& x1, int r) {
  x0 += x1;
  x1 = (x1 << r) | (x1 >> (32 - r));
  x1 ^= x0;
}

__device__ __forceinline__ void threefry2x32(uint32_t k0, uint32_t k1,
                                             uint32_t& x0, uint32_t& x1) {
  uint32_t k2 = k0 ^ k1 ^ 0x1BD11BDAu;
  x0 += k0; x1 += k1;
  tf_round(x0,x1,13); tf_round(x0,x1,15); tf_round(x0,x1,26); tf_round(x0,x1,6);
  x0 += k1; x1 += k2 + 1u;
  tf_round(x0,x1,17); tf_round(x0,x1,29); tf_round(x0,x1,16); tf_round(x0,x1,24);
  x0 += k2; x1 += k0 + 2u;
  tf_round(x0,x1,13); tf_round(x0,x1,15); tf_round(x0,x1,26); tf_round(x0,x1,6);
  x0 += k0; x1 += k1 + 3u;
  tf_round(x0,x1,17); tf_round(x0,x1,29); tf_round(x0,x1,16); tf_round(x0,x1,24);
  x0 += k1; x1 += k2 + 4u;
  tf_round(x0,x1,13); tf_round(x0,x1,15); tf_round(x0,x1,26); tf_round(x0,x1,6);
  x0 += k2; x1 += k0 + 5u;
}

// ---------------- small utility kernels ----------------
__global__ void zero_kernel(float* __restrict__ o, int n) {
  int i = blockIdx.x * blockDim.x + threadIdx.x;
  if (i < n) o[i] = 0.0f;
}

__global__ void copy_kernel(const float* __restrict__ a, float* __restrict__ o, int n) {
  int i = blockIdx.x * blockDim.x + threadIdx.x;
  if (i < n) o[i] = a[i];
}

// ---------------- weight repack: fp32 (a [+ b]) -> f16 hi/lo MFMA B-fragments ----
// Chunk (nt, s) = 16 cols x 32 k rows, laid out so a wave's b128 load at
// lane*16B yields the B fragment (n = lane&15, k = (lane>>4)*8 + j).
// hi chunk at ((nt*32+s)*2)*512, lo chunk at +512 (_Float16 units).
__global__ __launch_bounds__(256)
void repack_w(const float* __restrict__ Wa, const float* __restrict__ Wb,
              _Float16* __restrict__ pk, int N) {
  int gw = blockIdx.x * 4 + (threadIdx.x >> 6);
  int total = (N >> 4) * STOT;
  if (gw >= total) return;
  int nt = gw >> 5, s = gw & 31;
  int lane = threadIdx.x & 63;
  int quad = lane >> 4, lm = lane & 15;
  int col = nt * 16 + lm;
  half8 hi, lo;
#pragma unroll
  for (int j = 0; j < 8; ++j) {
    int row = s * 32 + quad * 8 + j;
    float v = Wa[(size_t)row * N + col];
    if (Wb) v += Wb[(size_t)row * N + col];
    _Float16 h = (_Float16)v;
    hi[j] = h;
    lo[j] = (_Float16)(v - (float)h);
  }
  _Float16* o = pk + ((size_t)(nt * 32 + s) * 2) * 512 + lane * 8;
  *(half8*)o = hi;
  *(half8*)(o + 512) = lo;
}

// ---------------- MFMA GEMM: P[ks] = A(64xK) @ W(KxN) over k-chunk ----------------
// A, W pre-packed as f16 hi/lo fragments. D = Ah*Wh + Al*Wh + Ah*Wl.
// Block: 256 threads = 4 waves; tile 64 rows x 256 cols (wave: 64x64).
__global__ __launch_bounds__(256, 1)
void mfma_gemm(const half8* __restrict__ Apk, const half8* __restrict__ Wpk,
               float* __restrict__ P, int N) {
  const int w = threadIdx.x >> 6;
  const int lane = threadIdx.x & 63;
  const int schunk = STOT / gridDim.y;
  const int s0 = blockIdx.y * schunk;
  const int send = s0 + schunk;
  const int nt0 = blockIdx.x * 16 + w * 4;

  floatx4 acc[4][4] = {};
  half8 a0[4][2], b0[4][2], a1[4][2], b1[4][2];

#define LOAD_FRAGS(s_, A_, B_)                                              \
  {                                                                         \
    _Pragma("unroll")                                                       \
    for (int mt = 0; mt < 4; ++mt) {                                        \
      const half8* ap = Apk + ((size_t)(mt * 32 + (s_)) * 2) * 64 + lane;   \
      A_[mt][0] = ap[0];                                                    \
      A_[mt][1] = ap[64];                                                   \
    }                                                                       \
    _Pragma("unroll")                                                       \
    for (int nt = 0; nt < 4; ++nt) {                                        \
      const half8* bp =                                                     \
          Wpk + ((size_t)((nt0 + nt) * 32 + (s_)) * 2) * 64 + lane;         \
      B_[nt][0] = bp[0];                                                    \
      B_[nt][1] = bp[64];                                                   \
    }                                                                       \
  }

#define DO_MFMA(A_, B_)                                                     \
  {                                                                         \
    _Pragma("unroll")                                                       \
    for (int mt = 0; mt < 4; ++mt) {                                        \
      _Pragma("unroll")                                                     \
      for (int nt = 0; nt < 4; ++nt) {                                      \
        acc[mt][nt] = __builtin_amdgcn_mfma_f32_16x16x32_f16(               \
            A_[mt][0], B_[nt][0], acc[mt][nt], 0, 0, 0);                    \
        acc[mt][nt] = __builtin_amdgcn_mfma_f32_16x16x32_f16(               \
            A_[mt][1], B_[nt][0], acc[mt][nt], 0, 0, 0);                    \
        acc[mt][nt] = __builtin_amdgcn_mfma_f32_16x16x32_f16(               \
            A_[mt][0], B_[nt][1], acc[mt][nt], 0, 0, 0);                    \
      }                                                                     \
    }                                                                       \
  }

  LOAD_FRAGS(s0, a0, b0);
  for (int s = s0; s < send; s += 2) {
    LOAD_FRAGS(s + 1, a1, b1);
    DO_MFMA(a0, b0);
    if (s + 2 < send) LOAD_FRAGS(s + 2, a0, b0);
    DO_MFMA(a1, b1);
  }
#undef LOAD_FRAGS
#undef DO_MFMA

  // C/D layout: col = lane&15, row = (lane>>4)*4 + r
  const int row0 = (lane >> 4) * 4;
  const int colb = blockIdx.x * 256 + w * 64 + (lane & 15);
  float* Pb = P + (size_t)blockIdx.y * 64 * N;
#pragma unroll
  for (int mt = 0; mt < 4; ++mt)
#pragma unroll
    for (int nt = 0; nt < 4; ++nt)
#pragma unroll
      for (int r = 0; r < 4; ++r)
        Pb[(size_t)(mt * 16 + row0 + r) * N + colb + nt * 16] = acc[mt][nt][r];
}

// ---------------- fp32 GEMM (encoder only, one-shot) ----------------
__global__ __launch_bounds__(256, 2)
void gemm64_kernel(const float* __restrict__ A, const float* __restrict__ W,
                   float* __restrict__ P, int K, int N) {
  const int vt = blockIdx.x;
  const int ks = blockIdx.y;
  const int kchunk = K / gridDim.y;
  const int kbase = ks * kchunk;
  const int v0 = vt * 256;

  __shared__ float As[32][68];
  __shared__ float Ws[32][256];

  float acc[8][8];
#pragma unroll
  for (int i = 0; i < 8; i++)
#pragma unroll
    for (int j = 0; j < 8; j++) acc[i][j] = 0.0f;

  const int tid = threadIdx.x;
  const int cg4 = (tid & 31) * 4;
  const int rg4 = (tid >> 5) * 4;

  for (int k0 = kbase; k0 < kbase + kchunk; k0 += 32) {
    __syncthreads();
    {
      int b  = tid >> 3;
      int f4 = tid & 7;
      const float* Ab = A + (size_t)b * K + k0 + f4 * 4;
      float4 a0 = *(const float4*)Ab;
      float4 a1 = *(const float4*)(Ab + (size_t)32 * K);
      int kk0 = f4 * 4;
      As[kk0+0][b] = a0.x; As[kk0+1][b] = a0.y; As[kk0+2][b] = a0.z; As[kk0+3][b] = a0.w;
      As[kk0+0][b+32] = a1.x; As[kk0+1][b+32] = a1.y; As[kk0+2][b+32] = a1.z; As[kk0+3][b+32] = a1.w;
    }
#pragma unroll
    for (int p = 0; p < 8; p++) {
      int idx = tid + p * 256;
      int row = idx >> 6, c4 = idx & 63;
      *(float4*)&Ws[row][c4 * 4] =
          *(const float4*)(W + (size_t)(k0 + row) * N + v0 + c4 * 4);
    }
    __syncthreads();

#pragma unroll 8
    for (int kk = 0; kk < 32; kk++) {
      float4 a0 = *(const float4*)&As[kk][rg4];
      float4 a1 = *(const float4*)&As[kk][32 + rg4];
      float4 w0 = *(const float4*)&Ws[kk][cg4];
      float4 w1 = *(const float4*)&Ws[kk][128 + cg4];
      float av[8] = {a0.x, a0.y, a0.z, a0.w, a1.x, a1.y, a1.z, a1.w};
      float wv[8] = {w0.x, w0.y, w0.z, w0.w, w1.x, w1.y, w1.z, w1.w};
#pragma unroll
      for (int i = 0; i < 8; i++)
#pragma unroll
        for (int j = 0; j < 8; j++)
          acc[i][j] = fmaf(av[i], wv[j], acc[i][j]);
    }
  }

  const size_t base = (size_t)ks * 64 * N;
#pragma unroll
  for (int i = 0; i < 8; i++) {
    int row = (i < 4) ? (rg4 + i) : (32 + rg4 + i - 4);
    float4 s0 = make_float4(acc[i][0], acc[i][1], acc[i][2], acc[i][3]);
    float4 s1 = make_float4(acc[i][4], acc[i][5], acc[i][6], acc[i][7]);
    *(float4*)(P + base + (size_t)row * N + v0 + cg4) = s0;
    *(float4*)(P + base + (size_t)row * N + v0 + 128 + cg4) = s1;
  }
}

// ---------------- LSTM gate fusion + A-fragment pack ----------------
__global__ void gates_kernel(const float* __restrict__ zp, int ksplit,
                             const float* __restrict__ bias,
                             const float* __restrict__ c_in,
                             float* __restrict__ h_out, float* __restrict__ c_out,
                             _Float16* __restrict__ hpk) {
  int tid = blockIdx.x * blockDim.x + threadIdx.x;
  if (tid >= B_DIM * H_DIM) return;
  int b = tid >> 10, j = tid & 1023;
  float zi = bias[j], zf = bias[j + 1024], zg = bias[j + 2048], zo = bias[j + 3072];
  const float* Pb = zp + (size_t)b * GATES;
  for (int p = 0; p < ksplit; p++) {
    const float* P = Pb + (size_t)p * B_DIM * GATES;
    zi += P[j]; zf += P[j + 1024]; zg += P[j + 2048]; zo += P[j + 3072];
  }
  float cp = c_in ? c_in[tid] : 0.0f;
  float si = 1.0f / (1.0f + expf(-zi));
  float sf = 1.0f / (1.0f + expf(-zf));
  float so = 1.0f / (1.0f + expf(-zo));
  float c = sf * cp + si * zg;
  c_out[tid] = c;
  float hv = so * c;
  h_out[tid] = hv;

  // pack into MFMA A-fragment hi/lo layout:
  // A[m = lane&15][k = quad*8 + jj], chunk (mt, s) at ((mt*32+s)*2)*512
  int mt = b >> 4, lm = b & 15;
  int s = j >> 5, quad = (j >> 3) & 3, jj = j & 7;
  size_t off = ((size_t)(mt * 32 + s) * 2) * 512 + (size_t)(quad * 16 + lm) * 8 + jj;
  _Float16 hh = (_Float16)hv;
  hpk[off] = hh;
  hpk[off + 512] = (_Float16)(hv - (float)hh);
}

// ---------------- sampling stage 1: per-chunk partials ----------------
__global__ __launch_bounds__(256)
void sample_stage1(const float* __restrict__ lp4, int ksplit,
                   const float* __restrict__ bd, int t,
                   float* __restrict__ pm, float* __restrict__ ps,
                   float* __restrict__ pt2, float* __restrict__ pbest,
                   int* __restrict__ pbi) {
  const int chunk = blockIdx.x;
  const int b = blockIdx.y;
  const int v = chunk * 256 + threadIdx.x;
  const size_t rowoff = (size_t)b * V_DIM;

  float l = bd[v];
  for (int p = 0; p < ksplit; p++)
    l += lp4[(size_t)p * B_DIM * V_DIM + rowoff + v];

  uint32_t tk0 = 0u, tk1 = (uint32_t)t;
  threefry2x32(0u, 1234u, tk0, tk1);
  uint32_t j = (uint32_t)(b * V_DIM + v);
#if RNG_PARTITIONABLE
  uint32_t y0 = 0u, y1 = j;
  threefry2x32(tk0, tk1, y0, y1);
  uint32_t bits = y0 ^ y1;
#else
  const uint32_t half = (uint32_t)(B_DIM * V_DIM / 2);
  uint32_t y0, y1;
  if (j < half) { y0 = j; y1 = j + half; } else { y0 = j - half; y1 = j; }
  threefry2x32(tk0, tk1, y0, y1);
  uint32_t bits = (j < half) ? y0 : y1;
#endif
  float u = __uint_as_float((bits >> 9) | 0x3f800000u) - 1.0f;
  u = fmaxf(u, 1.17549435e-38f);
  float g = -logf(-logf(u));
  float val = l + g;
  int bi = v;

  float m = l, bv = val;
  for (int off = 32; off > 0; off >>= 1) {
    m = fmaxf(m, __shfl_down(m, off));
    float ob = __shfl_down(bv, off);
    int   oi = __shfl_down(bi, off);
    if (ob > bv || (ob == bv && oi < bi)) { bv = ob; bi = oi; }
  }
  __shared__ float sm[4], sb2[4], ss[4], st[4];
  __shared__ int sbi[4];
  __shared__ float Msh;
  int wave = threadIdx.x >> 6, lane = threadIdx.x & 63;
  if (lane == 0) { sm[wave] = m; sb2[wave] = bv; sbi[wave] = bi; }
  __syncthreads();
  if (threadIdx.x == 0) {
    float M = sm[0], Bv = sb2[0]; int BI = sbi[0];
    for (int w = 1; w < 4; w++) {
      M = fmaxf(M, sm[w]);
      if (sb2[w] > Bv || (sb2[w] == Bv && sbi[w] < BI)) { Bv = sb2[w]; BI = sbi[w]; }
    }
    Msh = M;
    int o = b * NCHUNK + chunk;
    pm[o] = M; pbest[o] = Bv; pbi[o] = BI;
  }
  __syncthreads();
  float e = expf(l - Msh);
  float t2 = e * l;
  for (int off = 32; off > 0; off >>= 1) {
    e  += __shfl_down(e, off);
    t2 += __shfl_down(t2, off);
  }
  if (lane == 0) { ss[wave] = e; st[wave] = t2; }
  __syncthreads();
  if (threadIdx.x == 0) {
    int o = b * NCHUNK + chunk;
    ps[o]  = ss[0] + ss[1] + ss[2] + ss[3];
    pt2[o] = st[0] + st[1] + st[2] + st[3];
  }
}

// ---------------- sampling stage 2: reduce 125 chunks per row ----------------
__global__ __launch_bounds__(128)
void sample_stage2(const float* __restrict__ pm, const float* __restrict__ ps,
                   const float* __restrict__ pt2, const float* __restrict__ pbest,
                   const int* __restrict__ pbi,
                   const float* __restrict__ lp4, int ksplit,
                   const float* __restrict__ bd, int t, float* __restrict__ out) {
  const int b = blockIdx.x;
  const int tid = threadIdx.x;
  const int o = b * NCHUNK + tid;
  const bool valid = tid < NCHUNK;

  float m  = valid ? pm[o]    : -INFINITY;
  float bv = valid ? pbest[o] : -INFINITY;
  int   bi = valid ? pbi[o]   : 0x7fffffff;

  float M = m;
  for (int off = 32; off > 0; off >>= 1) M = fmaxf(M, __shfl_down(M, off));
  __shared__ float sM[2];
  int wave = tid >> 6, lane = tid & 63;
  if (lane == 0) sM[wave] = M;
  __syncthreads();
  const float Mg = fmaxf(sM[0], sM[1]);

  float sc = valid ? expf(m - Mg) : 0.0f;
  float s  = valid ? ps[o]  * sc : 0.0f;
  float t2 = valid ? pt2[o] * sc : 0.0f;
  for (int off = 32; off > 0; off >>= 1) {
    s  += __shfl_down(s, off);
    t2 += __shfl_down(t2, off);
    float ob = __shfl_down(bv, off);
    int   oi = __shfl_down(bi, off);
    if (ob > bv || (ob == bv && oi < bi)) { bv = ob; bi = oi; }
  }
  __shared__ float sS[2], sT[2], sB[2];
  __shared__ int sI[2];
  if (lane == 0) { sS[wave] = s; sT[wave] = t2; sB[wave] = bv; sI[wave] = bi; }
  __syncthreads();
  if (tid == 0) {
    float S = sS[0] + sS[1], T2 = sT[0] + sT[1];
    float Bv = sB[0]; int BI = sI[0];
    if (sB[1] > Bv || (sB[1] == Bv && sI[1] < BI)) { Bv = sB[1]; BI = sI[1]; }
    float lbest = bd[BI];
    for (int p = 0; p < ksplit; p++)
      lbest += lp4[(size_t)p * B_DIM * V_DIM + (size_t)b * V_DIM + BI];
    float lse = Mg + logf(S);
    out[(size_t)b * OUT_COLS + t]        = (float)BI;     // msg
    out[3968 + (size_t)b * OUT_COLS + t] = lbest - lse;   // log_prob
    out[7936 + (size_t)b * OUT_COLS + t] = lse - T2 / S;  // entropy
  }
}

// ---------------- launcher ----------------
extern "C" void kernel_launch(void* const* d_in, const int* in_sizes, int n_in,
                              void* d_out, int out_size, void* d_ws, size_t ws_size,
                              hipStream_t stream) {
  const float* inp = (const float*)d_in[0];
  const float* Wx1 = (const float*)d_in[1];
  // d_in[2] = Wh1: unused (encoder initial h == 0)
  const float* b1  = (const float*)d_in[3];
  const float* Wx2 = (const float*)d_in[4];
  const float* Wh2 = (const float*)d_in[5];
  const float* b2  = (const float*)d_in[6];
  const float* Wd  = (const float*)d_in[7];
  const float* bd  = (const float*)d_in[8];
  float* out = (float*)d_out;

  float* ws = (float*)d_ws;
  float* Wd_pk  = ws;                    // 32,768,000 floats (131 MB f16 hi/lo)
  float* W2_pk  = Wd_pk + 32768000;      //  4,194,304
  float* hpkf   = W2_pk + 4194304;       //     65,536
  float* zparts = hpkf + 65536;          //  2,097,152 (8 k-split parts)
  float* lparts = zparts + 2097152;      //  8,192,000 (4 k-split parts)
  float* h      = lparts + 8192000;      //     65,536
  float* c      = h + 65536;             //     65,536

  _Float16* hpk = (_Float16*)hpkf;

  // sampling partials alias zparts (dead during sampling phase)
  float* pm    = zparts;
  float* ps    = zparts + 8000;
  float* pt2   = zparts + 16000;
  float* pbest = zparts + 24000;
  int*   pbi   = (int*)(zparts + 32000);

  // one-time: repack Wd and (Wx2+Wh2) into f16 hi/lo MFMA fragments
  repack_w<<<16000, 256, 0, stream>>>(Wd, nullptr, (_Float16*)Wd_pk, V_DIM);
  repack_w<<<2048, 256, 0, stream>>>(Wx2, Wh2, (_Float16*)W2_pk, GATES);
  zero_kernel<<<47, 256, 0, stream>>>(out, 11904);

  // encoder: single step, zero initial state -> z = x@Wx1 + b1 (fp32, one-shot)
  gemm64_kernel<<<dim3(16, 4), 256, 0, stream>>>(inp, Wx1, zparts, E_DIM, GATES);
  gates_kernel<<<256, 256, 0, stream>>>(zparts, 4, b1, nullptr, h, c, hpk);

  for (int t = 0; t < T_STEPS; t++) {
    // state GEMM: z = h @ W2c  (64x1024x4096), k-split 8
    mfma_gemm<<<dim3(16, 8), 256, 0, stream>>>(
        (const half8*)hpk, (const half8*)W2_pk, zparts, GATES);
    gates_kernel<<<256, 256, 0, stream>>>(zparts, 8, b2, c, h, c, hpk);
    // logits GEMM: l = h @ Wd  (64x1024x32000), k-split 4
    mfma_gemm<<<dim3(125, 4), 256, 0, stream>>>(
        (const half8*)hpk, (const half8*)Wd_pk, lparts, V_DIM);
    sample_stage1<<<dim3(NCHUNK, B_DIM), 256, 0, stream>>>(lparts, 4, bd, t,
                                                           pm, ps, pt2, pbest, pbi);
    sample_stage2<<<B_DIM, 128, 0, stream>>>(pm, ps, pt2, pbest, pbi,
                                             lparts, 4, bd, t, out);
  }

  copy_kernel<<<256, 256, 0, stream>>>(h, out + 11904, B_DIM * H_DIM);
}